// Round 1
// baseline (314.581 us; speedup 1.0000x reference)
//
#include <hip/hip_runtime.h>
#include <math.h>

#define LEN 4096
#define LOG2LEN 12
#define DH 64
#define NBH 32      // B*H
#define KTOP 8
#define NGRP 8      // d-groups per (b,h) in pass A
#define DPG 8       // d's per group

#define PART_ELEMS (NBH * NGRP * LEN * 2)   // 2,097,152 floats (8 MB)
#define CORR_ELEMS (NBH * LEN)              // 131,072 floats

// ---------------------------------------------------------------------------
// Pass A: per (b,h, d-group): 8 forward FFTs of z = q_d + i*k_d (radix-2 DIF,
// natural in -> bit-reversed out), accumulate cross-spectrum partials
// P[f] = Q conj(K) = Im(A*B)/2 + i(|A|^2-|B|^2)/4, A=Z[f], B=Z[L-f].
// Stored in bit-reversed order (consumed as-is by the DIT inverse).
// ---------------------------------------------------------------------------
__global__ __launch_bounds__(256) void ac_fft_fwd(const float* __restrict__ q,
                                                  const float* __restrict__ k,
                                                  float* __restrict__ part) {
  __shared__ float re[LEN], im[LEN], sr[LEN], si[LEN];   // 64 KB
  __shared__ float twr[LEN / 2], twi[LEN / 2];           // 16 KB
  const int id = blockIdx.x;
  // pair-swizzle: blocks id and id+128 handle d-groups (2a, 2a+1) of the same
  // bh -> they share 64B cache lines and land on the same XCD (128 % 8 == 0).
  const int half = id >> 7;
  const int rem = id & 127;
  const int bh = rem >> 2;
  const int g = ((rem & 3) << 1) | half;
  const int tid = threadIdx.x;

  for (int j = tid; j < LEN / 2; j += 256) {
    float s, c;
    sincosf(-6.2831853071795864769f * (float)j / (float)LEN, &s, &c);
    twr[j] = c; twi[j] = s;
  }
  for (int p = tid; p < LEN; p += 256) { sr[p] = 0.f; si[p] = 0.f; }

  const float* qb = q + (size_t)bh * LEN * DH;
  const float* kb = k + (size_t)bh * LEN * DH;

  for (int dd = 0; dd < DPG; ++dd) {
    const int d = g * DPG + dd;
    __syncthreads();  // prior iteration's spectrum reads done; twiddles ready
    for (int t = tid; t < LEN; t += 256) {
      re[t] = qb[(size_t)t * DH + d];
      im[t] = kb[(size_t)t * DH + d];
    }
    __syncthreads();
    // forward DIF radix-2: h = half-size, 12 stages
    for (int h = LEN / 2; h >= 1; h >>= 1) {
      const int tstep = (LEN / 2) / h;  // twiddle index stride
      for (int m = tid; m < LEN / 2; m += 256) {
        const int jj = m & (h - 1);
        const int i1 = ((m & ~(h - 1)) << 1) | jj;
        const int i2 = i1 + h;
        float ur = re[i1], ui = im[i1];
        float vr = re[i2], vi = im[i2];
        re[i1] = ur + vr; im[i1] = ui + vi;
        float dr = ur - vr, di = ui - vi;
        float wr = twr[jj * tstep], wi = twi[jj * tstep];
        re[i2] = dr * wr - di * wi;
        im[i2] = dr * wi + di * wr;
      }
      __syncthreads();
    }
    // accumulate cross-spectrum (position p holds Z[bitrev(p)])
    for (int p = tid; p < LEN; p += 256) {
      const int f = __brev((unsigned)p) >> (32 - LOG2LEN);
      const int f2 = (LEN - f) & (LEN - 1);
      const int p2 = __brev((unsigned)f2) >> (32 - LOG2LEN);
      float ar = re[p], ai = im[p];
      float br = re[p2], bi = im[p2];
      sr[p] += 0.5f * (ar * bi + ai * br);
      si[p] += 0.25f * ((ar * ar + ai * ai) - (br * br + bi * bi));
    }
  }
  __syncthreads();
  float* op = part + (size_t)(bh * NGRP + g) * LEN * 2;
  for (int p = tid; p < LEN; p += 256) {
    op[2 * p] = sr[p];
    op[2 * p + 1] = si[p];
  }
}

// ---------------------------------------------------------------------------
// Pass B: per (b,h): sum the 8 partial spectra, inverse radix-2 DIT
// (bit-reversed in -> natural out), scale by 1/(L*Dh), write corr.
// ---------------------------------------------------------------------------
__global__ __launch_bounds__(256) void ac_fft_inv(const float* __restrict__ part,
                                                  float* __restrict__ corr) {
  __shared__ float re[LEN], im[LEN];            // 32 KB
  __shared__ float twr[LEN / 2], twi[LEN / 2];  // 16 KB
  const int bh = blockIdx.x;
  const int tid = threadIdx.x;
  for (int j = tid; j < LEN / 2; j += 256) {
    float s, c;
    sincosf(6.2831853071795864769f * (float)j / (float)LEN, &s, &c);
    twr[j] = c; twi[j] = s;
  }
  for (int p = tid; p < LEN; p += 256) {
    float accr = 0.f, acci = 0.f;
    for (int gg = 0; gg < NGRP; ++gg) {
      const float* pp = part + (size_t)(bh * NGRP + gg) * LEN * 2;
      accr += pp[2 * p];
      acci += pp[2 * p + 1];
    }
    re[p] = accr; im[p] = acci;
  }
  __syncthreads();
  // inverse DIT radix-2: h = 1 .. 2048
  for (int h = 1; h <= LEN / 2; h <<= 1) {
    const int tstep = (LEN / 2) / h;
    for (int m = tid; m < LEN / 2; m += 256) {
      const int jj = m & (h - 1);
      const int i1 = ((m & ~(h - 1)) << 1) | jj;
      const int i2 = i1 + h;
      float wr = twr[jj * tstep], wi = twi[jj * tstep];
      float vr = re[i2], vi = im[i2];
      float tr = vr * wr - vi * wi;
      float ti = vr * wi + vi * wr;
      float ur = re[i1], ui = im[i1];
      re[i1] = ur + tr; im[i1] = ui + ti;
      re[i2] = ur - tr; im[i2] = ui - ti;
    }
    __syncthreads();
  }
  const float scale = 1.0f / ((float)LEN * (float)DH);
  for (int t = tid; t < LEN; t += 256) corr[(size_t)bh * LEN + t] = re[t] * scale;
}

// ---------------------------------------------------------------------------
// Pass C: per (b,h): top-8 of corr (8 serial max-reductions) + softmax.
// ---------------------------------------------------------------------------
__global__ __launch_bounds__(256) void ac_topk(const float* __restrict__ corr,
                                               float* __restrict__ attn,
                                               int* __restrict__ delays) {
  __shared__ float vals[LEN];  // 16 KB
  __shared__ float rv[256];
  __shared__ int ri[256];
  __shared__ float selv[KTOP];
  __shared__ int seli[KTOP];
  const int bh = blockIdx.x, tid = threadIdx.x;
  for (int t = tid; t < LEN; t += 256) vals[t] = corr[(size_t)bh * LEN + t];
  __syncthreads();
  for (int kk = 0; kk < KTOP; ++kk) {
    float mv = -3.0e38f;
    int mi = 0;
    for (int t = tid; t < LEN; t += 256) {
      float x = vals[t];
      if (x > mv) { mv = x; mi = t; }
    }
    rv[tid] = mv; ri[tid] = mi;
    __syncthreads();
    for (int s = 128; s > 0; s >>= 1) {
      if (tid < s) {
        if (rv[tid + s] > rv[tid]) { rv[tid] = rv[tid + s]; ri[tid] = ri[tid + s]; }
      }
      __syncthreads();
    }
    if (tid == 0) {
      selv[kk] = rv[0];
      seli[kk] = ri[0];
      vals[ri[0]] = -3.0e38f;  // knock out the winner
    }
    __syncthreads();
  }
  if (tid == 0) {
    float mx = selv[0];  // first extracted is the global max
    float ex[KTOP];
    float sum = 0.f;
    for (int j = 0; j < KTOP; ++j) { ex[j] = expf(selv[j] - mx); sum += ex[j]; }
    float inv = 1.0f / sum;
    for (int j = 0; j < KTOP; ++j) {
      attn[bh * KTOP + j] = ex[j] * inv;
      delays[bh * KTOP + j] = seli[j];
    }
  }
}

// ---------------------------------------------------------------------------
// Pass D: out[bh,t,d] = sum_j attn_j * v[bh,(t-delay_j) mod L, d], float4.
// XCD-swizzled: each XCD owns 4 bh slabs (4 MB of v = one L2).
// ---------------------------------------------------------------------------
__global__ __launch_bounds__(256) void ac_gather(const float* __restrict__ v,
                                                 const float* __restrict__ attn,
                                                 const int* __restrict__ delays,
                                                 float* __restrict__ out) {
  const int bx = blockIdx.x;
  const int xcd = bx & 7;
  const int i = bx >> 3;          // [0,1024)
  const int bh = (xcd << 2) | (i & 3);
  const int chunk = i >> 2;       // [0,256)
  const int tid = threadIdx.x;
  float aw[KTOP];
  int dl[KTOP];
#pragma unroll
  for (int j = 0; j < KTOP; ++j) {
    aw[j] = attn[bh * KTOP + j];
    dl[j] = delays[bh * KTOP + j];
  }
  const int e = chunk * 1024 + tid * 4;  // element offset within bh slab
  const int t = e >> 6;
  const int d = e & 63;
  const float* vb = v + (size_t)bh * LEN * DH;
  float4 acc = make_float4(0.f, 0.f, 0.f, 0.f);
#pragma unroll
  for (int j = 0; j < KTOP; ++j) {
    int src = t - dl[j];
    if (src < 0) src += LEN;
    const float4 vv = *reinterpret_cast<const float4*>(vb + (size_t)src * DH + d);
    acc.x += aw[j] * vv.x;
    acc.y += aw[j] * vv.y;
    acc.z += aw[j] * vv.z;
    acc.w += aw[j] * vv.w;
  }
  *reinterpret_cast<float4*>(out + (size_t)bh * LEN * DH + e) = acc;
}

extern "C" void kernel_launch(void* const* d_in, const int* in_sizes, int n_in,
                              void* d_out, int out_size, void* d_ws, size_t ws_size,
                              hipStream_t stream) {
  const float* q = (const float*)d_in[0];
  const float* k = (const float*)d_in[1];
  const float* v = (const float*)d_in[2];
  float* out = (float*)d_out;
  float* ws = (float*)d_ws;

  float* part = ws;                       // 8 MB of partial spectra
  float* corr = ws + PART_ELEMS;          // 0.5 MB
  float* attn = corr + CORR_ELEMS;        // 256 floats
  int* delays = (int*)(attn + NBH * KTOP);// 256 ints

  ac_fft_fwd<<<dim3(NBH * NGRP), dim3(256), 0, stream>>>(q, k, part);
  ac_fft_inv<<<dim3(NBH), dim3(256), 0, stream>>>(part, corr);
  ac_topk<<<dim3(NBH), dim3(256), 0, stream>>>(corr, attn, delays);
  ac_gather<<<dim3(NBH * 256), dim3(256), 0, stream>>>(v, attn, delays, out);
}

// Round 2
// 179.812 us; speedup vs baseline: 1.7495x; 1.7495x over previous
//
#include <hip/hip_runtime.h>
#include <math.h>

#define LEN 4096
#define LOG2LEN 12
#define DH 64
#define NBH 32      // B*H
#define KTOP 8
#define NGRP 8      // d-groups per (b,h) in pass A
#define DPG 8       // d's per group

#define PART_ELEMS (NBH * NGRP * LEN * 2)   // 2,097,152 floats (8 MB)
#define CORR_ELEMS (NBH * LEN)              // 131,072 floats
#define ZT_ELEMS ((size_t)NBH * DH * LEN)   // float2 count (64 MB)

// base-4 digit reversal of a 12-bit index: bit-reverse, then swap bit pairs
__device__ __forceinline__ int rev4_12(int x) {
  unsigned r = __brev((unsigned)x) >> 20;
  return (int)(((r & 0x555u) << 1) | ((r >> 1) & 0x555u));
}

// twiddle fetch from half-size (2048) table; e in [0, 3*LEN/4)
__device__ __forceinline__ void twget(const float* __restrict__ twr,
                                      const float* __restrict__ twi,
                                      int e, float& wr, float& wi) {
  const int idx = e & (LEN / 2 - 1);
  const float s = (e & (LEN / 2)) ? -1.0f : 1.0f;
  wr = s * twr[idx];
  wi = s * twi[idx];
}

// ---------------------------------------------------------------------------
// Pass T: transpose q,k (bh,t,d) -> packed complex zT[(bh*64+d)*LEN + t],
// z = q + i*k. Coalesced both sides via padded LDS tiles.
// ---------------------------------------------------------------------------
__global__ __launch_bounds__(256, 4) void ac_transpose(const float* __restrict__ q,
                                                       const float* __restrict__ k,
                                                       float2* __restrict__ zT) {
  __shared__ float tq[64][65], tk[64][65];
  const int bh = blockIdx.x >> 6;
  const int t0 = (blockIdx.x & 63) * 64;
  const int tid = threadIdx.x;
  const int tl = tid >> 2;   // row 0..63
  const int c = tid & 3;
  const float* qb = q + ((size_t)bh * LEN + t0) * DH;
  const float* kb = k + ((size_t)bh * LEN + t0) * DH;
#pragma unroll
  for (int r = 0; r < 4; ++r) {
    const int d0 = (c + r * 4) * 4;
    const float4 vq = *reinterpret_cast<const float4*>(qb + (size_t)tl * DH + d0);
    const float4 vk = *reinterpret_cast<const float4*>(kb + (size_t)tl * DH + d0);
    tq[tl][d0] = vq.x; tq[tl][d0 + 1] = vq.y; tq[tl][d0 + 2] = vq.z; tq[tl][d0 + 3] = vq.w;
    tk[tl][d0] = vk.x; tk[tl][d0 + 1] = vk.y; tk[tl][d0 + 2] = vk.z; tk[tl][d0 + 3] = vk.w;
  }
  __syncthreads();
  const int d = tid >> 2;
  const int s = tid & 3;
  float2* ob = zT + ((size_t)(bh * DH + d)) * LEN + t0;
#pragma unroll
  for (int r = 0; r < 8; ++r) {
    const int t = (s + r * 4) * 2;
    const float4 o = make_float4(tq[t][d], tk[t][d], tq[t + 1][d], tk[t + 1][d]);
    *reinterpret_cast<float4*>(&ob[t]) = o;
  }
}

// ---------------------------------------------------------------------------
// Pass A: per (b,h,d-group): 8 forward FFTs of z = q_d + i*k_d, radix-4 DIF
// (natural in -> base-4-digit-reversed out), accumulate cross-spectrum in
// REGISTERS: P[f] = Q conj(K) = Im(A*B)/2 + i(|A|^2-|B|^2)/4, A=Z[f], B=Z[-f].
// Stored digit-reversed (consumed as-is by the radix-4 DIT inverse).
// ---------------------------------------------------------------------------
template <bool TR>
__global__ __launch_bounds__(256, 3) void ac_fft_fwd(const float* __restrict__ q,
                                                     const float* __restrict__ k,
                                                     const float2* __restrict__ zT,
                                                     float* __restrict__ part) {
  __shared__ float re[LEN], im[LEN];            // 32 KB
  __shared__ float twr[LEN / 2], twi[LEN / 2];  // 16 KB
  const int id = blockIdx.x;
  const int half = id >> 7;
  const int rem = id & 127;
  const int bh = rem >> 2;
  const int g = ((rem & 3) << 1) | half;
  const int tid = threadIdx.x;

  for (int j = tid; j < LEN / 2; j += 256) {
    float s, c;
    sincosf(-6.2831853071795864769f * (float)j / (float)LEN, &s, &c);
    twr[j] = c; twi[j] = s;
  }
  float srg[16], sig[16];
#pragma unroll
  for (int i = 0; i < 16; ++i) { srg[i] = 0.f; sig[i] = 0.f; }

  const float* qb = q + (size_t)bh * LEN * DH;
  const float* kb = k + (size_t)bh * LEN * DH;

  for (int dd = 0; dd < DPG; ++dd) {
    const int d = g * DPG + dd;
    __syncthreads();  // prior iteration's LDS reads done; twiddles ready
    if (TR) {
      const float2* zb = zT + (size_t)(bh * DH + d) * LEN;
      for (int t = tid; t < LEN; t += 256) {
        const float2 z = zb[t];
        re[t] = z.x; im[t] = z.y;
      }
    } else {
      for (int t = tid; t < LEN; t += 256) {
        re[t] = qb[(size_t)t * DH + d];
        im[t] = kb[(size_t)t * DH + d];
      }
    }
    __syncthreads();
    // forward radix-4 DIF: 6 stages, quarter q4 = 1024 .. 1
    for (int q4 = LEN / 4; q4 >= 1; q4 >>= 2) {
      const int tmul = (LEN / 4) / q4;
      for (int m = tid; m < LEN / 4; m += 256) {
        const int j = m & (q4 - 1);
        const int i0 = ((m & ~(q4 - 1)) << 2) | j;
        const int i1 = i0 + q4, i2 = i0 + 2 * q4, i3 = i0 + 3 * q4;
        const float x0r = re[i0], x0i = im[i0];
        const float x1r = re[i1], x1i = im[i1];
        const float x2r = re[i2], x2i = im[i2];
        const float x3r = re[i3], x3i = im[i3];
        const float t0r = x0r + x2r, t0i = x0i + x2i;
        const float t1r = x0r - x2r, t1i = x0i - x2i;
        const float t2r = x1r + x3r, t2i = x1i + x3i;
        const float t3r = x1r - x3r, t3i = x1i - x3i;
        const float u0r = t0r + t2r, u0i = t0i + t2i;
        const float u2r = t0r - t2r, u2i = t0i - t2i;
        const float u1r = t1r + t3i, u1i = t1i - t3r;  // t1 - i*t3
        const float u3r = t1r - t3i, u3i = t1i + t3r;  // t1 + i*t3
        re[i0] = u0r; im[i0] = u0i;
        const int e = tmul * j;
        float w1r, w1i, w2r, w2i, w3r, w3i;
        twget(twr, twi, e, w1r, w1i);
        twget(twr, twi, 2 * e, w2r, w2i);
        twget(twr, twi, 3 * e, w3r, w3i);
        re[i1] = u1r * w1r - u1i * w1i; im[i1] = u1r * w1i + u1i * w1r;
        re[i2] = u2r * w2r - u2i * w2i; im[i2] = u2r * w2i + u2i * w2r;
        re[i3] = u3r * w3r - u3i * w3i; im[i3] = u3r * w3i + u3i * w3r;
      }
      __syncthreads();
    }
    // accumulate cross-spectrum into registers (position p holds Z[rev4(p)])
#pragma unroll
    for (int i = 0; i < 16; ++i) {
      const int p = tid + 256 * i;
      const int f = rev4_12(p);
      const int f2 = (LEN - f) & (LEN - 1);
      const int p2 = rev4_12(f2);
      const float ar = re[p], ai = im[p];
      const float br = re[p2], bi = im[p2];
      srg[i] += 0.5f * (ar * bi + ai * br);
      sig[i] += 0.25f * ((ar * ar + ai * ai) - (br * br + bi * bi));
    }
  }
  float2* op = (float2*)(part + (size_t)(bh * NGRP + g) * LEN * 2);
#pragma unroll
  for (int i = 0; i < 16; ++i) {
    const int p = tid + 256 * i;
    op[p] = make_float2(srg[i], sig[i]);
  }
}

// ---------------------------------------------------------------------------
// Pass B: per (b,h): sum the 8 partial spectra, inverse radix-4 DIT
// (digit-reversed in -> natural out), scale by 1/(L*Dh), write corr.
// ---------------------------------------------------------------------------
__global__ __launch_bounds__(256, 3) void ac_fft_inv(const float* __restrict__ part,
                                                     float* __restrict__ corr) {
  __shared__ float re[LEN], im[LEN];
  __shared__ float twr[LEN / 2], twi[LEN / 2];
  const int bh = blockIdx.x;
  const int tid = threadIdx.x;
  for (int j = tid; j < LEN / 2; j += 256) {
    float s, c;
    sincosf(6.2831853071795864769f * (float)j / (float)LEN, &s, &c);
    twr[j] = c; twi[j] = s;
  }
  for (int p = tid; p < LEN; p += 256) {
    float accr = 0.f, acci = 0.f;
    for (int gg = 0; gg < NGRP; ++gg) {
      const float2 v = ((const float2*)(part + (size_t)(bh * NGRP + gg) * LEN * 2))[p];
      accr += v.x; acci += v.y;
    }
    re[p] = accr; im[p] = acci;
  }
  __syncthreads();
  // inverse radix-4 DIT: quarter q4 = 1 .. 1024
  for (int q4 = 1; q4 <= LEN / 4; q4 <<= 2) {
    const int tmul = (LEN / 4) / q4;
    for (int m = tid; m < LEN / 4; m += 256) {
      const int j = m & (q4 - 1);
      const int i0 = ((m & ~(q4 - 1)) << 2) | j;
      const int i1 = i0 + q4, i2 = i0 + 2 * q4, i3 = i0 + 3 * q4;
      const int e = tmul * j;
      float w1r, w1i, w2r, w2i, w3r, w3i;
      twget(twr, twi, e, w1r, w1i);
      twget(twr, twi, 2 * e, w2r, w2i);
      twget(twr, twi, 3 * e, w3r, w3i);
      const float x0r = re[i0], x0i = im[i0];
      float y1r = re[i1], y1i = im[i1];
      float y2r = re[i2], y2i = im[i2];
      float y3r = re[i3], y3i = im[i3];
      const float x1r = y1r * w1r - y1i * w1i, x1i = y1r * w1i + y1i * w1r;
      const float x2r = y2r * w2r - y2i * w2i, x2i = y2r * w2i + y2i * w2r;
      const float x3r = y3r * w3r - y3i * w3i, x3i = y3r * w3i + y3i * w3r;
      const float t0r = x0r + x2r, t0i = x0i + x2i;
      const float t1r = x0r - x2r, t1i = x0i - x2i;
      const float t2r = x1r + x3r, t2i = x1i + x3i;
      const float t3r = x1r - x3r, t3i = x1i - x3i;
      re[i0] = t0r + t2r; im[i0] = t0i + t2i;
      re[i2] = t0r - t2r; im[i2] = t0i - t2i;
      re[i1] = t1r - t3i; im[i1] = t1i + t3r;  // t1 + i*t3
      re[i3] = t1r + t3i; im[i3] = t1i - t3r;  // t1 - i*t3
    }
    __syncthreads();
  }
  const float scale = 1.0f / ((float)LEN * (float)DH);
  for (int t = tid; t < LEN; t += 256) corr[(size_t)bh * LEN + t] = re[t] * scale;
}

// ---------------------------------------------------------------------------
// Pass C: per (b,h): top-8 of corr (8 serial max-reductions) + softmax.
// ---------------------------------------------------------------------------
__global__ __launch_bounds__(256) void ac_topk(const float* __restrict__ corr,
                                               float* __restrict__ attn,
                                               int* __restrict__ delays) {
  __shared__ float vals[LEN];
  __shared__ float rv[256];
  __shared__ int ri[256];
  __shared__ float selv[KTOP];
  __shared__ int seli[KTOP];
  const int bh = blockIdx.x, tid = threadIdx.x;
  for (int t = tid; t < LEN; t += 256) vals[t] = corr[(size_t)bh * LEN + t];
  __syncthreads();
  for (int kk = 0; kk < KTOP; ++kk) {
    float mv = -3.0e38f;
    int mi = 0;
    for (int t = tid; t < LEN; t += 256) {
      const float x = vals[t];
      if (x > mv) { mv = x; mi = t; }
    }
    rv[tid] = mv; ri[tid] = mi;
    __syncthreads();
    for (int s = 128; s > 0; s >>= 1) {
      if (tid < s) {
        if (rv[tid + s] > rv[tid]) { rv[tid] = rv[tid + s]; ri[tid] = ri[tid + s]; }
      }
      __syncthreads();
    }
    if (tid == 0) {
      selv[kk] = rv[0];
      seli[kk] = ri[0];
      vals[ri[0]] = -3.0e38f;
    }
    __syncthreads();
  }
  if (tid == 0) {
    const float mx = selv[0];
    float ex[KTOP];
    float sum = 0.f;
    for (int j = 0; j < KTOP; ++j) { ex[j] = expf(selv[j] - mx); sum += ex[j]; }
    const float inv = 1.0f / sum;
    for (int j = 0; j < KTOP; ++j) {
      attn[bh * KTOP + j] = ex[j] * inv;
      delays[bh * KTOP + j] = seli[j];
    }
  }
}

// ---------------------------------------------------------------------------
// Pass D: out[bh,t,d] = sum_j attn_j * v[bh,(t-delay_j) mod L, d], float4.
// ---------------------------------------------------------------------------
__global__ __launch_bounds__(256) void ac_gather(const float* __restrict__ v,
                                                 const float* __restrict__ attn,
                                                 const int* __restrict__ delays,
                                                 float* __restrict__ out) {
  const int bx = blockIdx.x;
  const int xcd = bx & 7;
  const int i = bx >> 3;
  const int bh = (xcd << 2) | (i & 3);
  const int chunk = i >> 2;
  const int tid = threadIdx.x;
  float aw[KTOP];
  int dl[KTOP];
#pragma unroll
  for (int j = 0; j < KTOP; ++j) {
    aw[j] = attn[bh * KTOP + j];
    dl[j] = delays[bh * KTOP + j];
  }
  const int e = chunk * 1024 + tid * 4;
  const int t = e >> 6;
  const int d = e & 63;
  const float* vb = v + (size_t)bh * LEN * DH;
  float4 acc = make_float4(0.f, 0.f, 0.f, 0.f);
#pragma unroll
  for (int j = 0; j < KTOP; ++j) {
    int src = t - dl[j];
    if (src < 0) src += LEN;
    const float4 vv = *reinterpret_cast<const float4*>(vb + (size_t)src * DH + d);
    acc.x += aw[j] * vv.x;
    acc.y += aw[j] * vv.y;
    acc.z += aw[j] * vv.z;
    acc.w += aw[j] * vv.w;
  }
  *reinterpret_cast<float4*>(out + (size_t)bh * LEN * DH + e) = acc;
}

extern "C" void kernel_launch(void* const* d_in, const int* in_sizes, int n_in,
                              void* d_out, int out_size, void* d_ws, size_t ws_size,
                              hipStream_t stream) {
  const float* q = (const float*)d_in[0];
  const float* k = (const float*)d_in[1];
  const float* v = (const float*)d_in[2];
  float* out = (float*)d_out;

  const size_t tail_floats = (size_t)PART_ELEMS + CORR_ELEMS + NBH * KTOP + NBH * KTOP;
  const size_t need = ZT_ELEMS * sizeof(float2) + tail_floats * sizeof(float);
  const bool tr = (ws_size >= need);

  float2* zT;
  float* part;
  if (tr) {
    zT = (float2*)d_ws;
    part = (float*)(zT + ZT_ELEMS);
  } else {
    zT = nullptr;
    part = (float*)d_ws;
  }
  float* corr = part + PART_ELEMS;
  float* attn = corr + CORR_ELEMS;
  int* delays = (int*)(attn + NBH * KTOP);

  if (tr) {
    ac_transpose<<<dim3(NBH * 64), dim3(256), 0, stream>>>(q, k, zT);
    ac_fft_fwd<true><<<dim3(NBH * NGRP), dim3(256), 0, stream>>>(q, k, zT, part);
  } else {
    ac_fft_fwd<false><<<dim3(NBH * NGRP), dim3(256), 0, stream>>>(q, k, zT, part);
  }
  ac_fft_inv<<<dim3(NBH), dim3(256), 0, stream>>>(part, corr);
  ac_topk<<<dim3(NBH), dim3(256), 0, stream>>>(corr, attn, delays);
  ac_gather<<<dim3(NBH * 256), dim3(256), 0, stream>>>(v, attn, delays, out);
}

// Round 3
// 149.175 us; speedup vs baseline: 2.1088x; 1.2054x over previous
//
#include <hip/hip_runtime.h>
#include <math.h>

#define LEN 4096
#define LOG2LEN 12
#define DH 64
#define NBH 32      // B*H
#define KTOP 8

#define CORR_ELEMS (NBH * LEN)              // 131,072 floats
#define ZT_ELEMS ((size_t)NBH * DH * LEN)   // float2 count (64 MB)
#define TW_N (LEN / 2)                      // 2048 float2 twiddles

// padded LDS index: kills stride-2^k bank conflicts (stride-4 stage becomes
// perfectly conflict-free; others <=4-way which is ~free on CDNA4)
#define PAD(i) ((i) + ((i) >> 5))
#define PAD_LEN (LEN + LEN / 32)

// base-4 digit reversal of a 12-bit index: bit-reverse, then swap bit pairs
__device__ __forceinline__ int rev4_12(int x) {
  unsigned r = __brev((unsigned)x) >> 20;
  return (int)(((r & 0x555u) << 1) | ((r >> 1) & 0x555u));
}

// twiddle fetch from global half-table tw[j] = (cos(2pi j/L), sin(2pi j/L));
// SIM = -1 forward, +1 inverse. e in [0, 3*LEN/4).
template <int SIM>
__device__ __forceinline__ void twget(const float2* __restrict__ tw, int e,
                                      float& wr, float& wi) {
  const float2 t = tw[e & (TW_N - 1)];
  const float sgn = (e & TW_N) ? -1.0f : 1.0f;
  wr = sgn * t.x;
  wi = sgn * (float)SIM * t.y;
}

// ---------------------------------------------------------------------------
// twiddle table init: tw[j] = (cos, sin)(2 pi j / LEN), j in [0, 2048)
// ---------------------------------------------------------------------------
__global__ void ac_twinit(float2* __restrict__ tw) {
  const int j = blockIdx.x * 256 + threadIdx.x;
  if (j < TW_N) {
    float s, c;
    sincosf(6.2831853071795864769f * (float)j / (float)LEN, &s, &c);
    tw[j] = make_float2(c, s);
  }
}

// ---------------------------------------------------------------------------
// Pass T: transpose q,k (bh,t,d) -> packed complex zT[(bh*64+d)*LEN + t],
// z = q + i*k. Coalesced both sides via padded LDS tiles.
// ---------------------------------------------------------------------------
__global__ __launch_bounds__(256, 4) void ac_transpose(const float* __restrict__ q,
                                                       const float* __restrict__ k,
                                                       float2* __restrict__ zT) {
  __shared__ float tq[64][65], tk[64][65];
  const int bh = blockIdx.x >> 6;
  const int t0 = (blockIdx.x & 63) * 64;
  const int tid = threadIdx.x;
  const int tl = tid >> 2;   // row 0..63
  const int c = tid & 3;
  const float* qb = q + ((size_t)bh * LEN + t0) * DH;
  const float* kb = k + ((size_t)bh * LEN + t0) * DH;
#pragma unroll
  for (int r = 0; r < 4; ++r) {
    const int d0 = (c + r * 4) * 4;
    const float4 vq = *reinterpret_cast<const float4*>(qb + (size_t)tl * DH + d0);
    const float4 vk = *reinterpret_cast<const float4*>(kb + (size_t)tl * DH + d0);
    tq[tl][d0] = vq.x; tq[tl][d0 + 1] = vq.y; tq[tl][d0 + 2] = vq.z; tq[tl][d0 + 3] = vq.w;
    tk[tl][d0] = vk.x; tk[tl][d0 + 1] = vk.y; tk[tl][d0 + 2] = vk.z; tk[tl][d0 + 3] = vk.w;
  }
  __syncthreads();
  const int d = tid >> 2;
  const int s = tid & 3;
  float2* ob = zT + ((size_t)(bh * DH + d)) * LEN + t0;
#pragma unroll
  for (int r = 0; r < 8; ++r) {
    const int t = (s + r * 4) * 2;
    const float4 o = make_float4(tq[t][d], tk[t][d], tq[t + 1][d], tk[t + 1][d]);
    *reinterpret_cast<float4*>(&ob[t]) = o;
  }
}

// ---------------------------------------------------------------------------
// Pass A: per (b,h, d-group of DPB): forward FFTs of z = q_d + i*k_d, radix-4
// DIF (natural in -> base-4-digit-reversed out), cross-spectrum accumulated in
// registers: P[f] = Q conj(K) = Im(A*B)/2 + i(|A|^2-|B|^2)/4, A=Z[f], B=Z[-f].
// Partials stored digit-reversed (consumed as-is by the radix-4 DIT inverse).
// ---------------------------------------------------------------------------
template <int DPB, bool TR>
__global__ __launch_bounds__(256, 4) void ac_fft_fwd(const float* __restrict__ q,
                                                     const float* __restrict__ k,
                                                     const float2* __restrict__ zT,
                                                     const float2* __restrict__ tw,
                                                     float2* __restrict__ part) {
  __shared__ float re[PAD_LEN], im[PAD_LEN];  // ~34 KB
  const int nb = DH / DPB;                    // blocks per bh
  const int bh = blockIdx.x / nb;
  const int g = blockIdx.x % nb;
  const int tid = threadIdx.x;

  float srg[16], sig[16];
#pragma unroll
  for (int i = 0; i < 16; ++i) { srg[i] = 0.f; sig[i] = 0.f; }

  const float* qb = q + (size_t)bh * LEN * DH;
  const float* kb = k + (size_t)bh * LEN * DH;

  for (int dd = 0; dd < DPB; ++dd) {
    const int d = g * DPB + dd;
    __syncthreads();  // prior iteration's LDS reads done
    if (TR) {
      const float2* zb = zT + (size_t)(bh * DH + d) * LEN;
      for (int t = tid; t < LEN; t += 256) {
        const float2 z = zb[t];
        re[PAD(t)] = z.x; im[PAD(t)] = z.y;
      }
    } else {
      for (int t = tid; t < LEN; t += 256) {
        re[PAD(t)] = qb[(size_t)t * DH + d];
        im[PAD(t)] = kb[(size_t)t * DH + d];
      }
    }
    __syncthreads();
    // forward radix-4 DIF: 6 stages, quarter q4 = 1024 .. 1
    int tmul = 1;
    for (int q4 = LEN / 4; q4 >= 1; q4 >>= 2, tmul <<= 2) {
#pragma unroll 4
      for (int m = tid; m < LEN / 4; m += 256) {
        const int j = m & (q4 - 1);
        const int i0 = ((m & ~(q4 - 1)) << 2) | j;
        const int i1 = i0 + q4, i2 = i0 + 2 * q4, i3 = i0 + 3 * q4;
        const int p0 = PAD(i0), p1 = PAD(i1), p2_ = PAD(i2), p3 = PAD(i3);
        const float x0r = re[p0], x0i = im[p0];
        const float x1r = re[p1], x1i = im[p1];
        const float x2r = re[p2_], x2i = im[p2_];
        const float x3r = re[p3], x3i = im[p3];
        const float t0r = x0r + x2r, t0i = x0i + x2i;
        const float t1r = x0r - x2r, t1i = x0i - x2i;
        const float t2r = x1r + x3r, t2i = x1i + x3i;
        const float t3r = x1r - x3r, t3i = x1i - x3i;
        const float u0r = t0r + t2r, u0i = t0i + t2i;
        const float u2r = t0r - t2r, u2i = t0i - t2i;
        const float u1r = t1r + t3i, u1i = t1i - t3r;  // t1 - i*t3
        const float u3r = t1r - t3i, u3i = t1i + t3r;  // t1 + i*t3
        re[p0] = u0r; im[p0] = u0i;
        const int e = tmul * j;
        float w1r, w1i, w2r, w2i, w3r, w3i;
        twget<-1>(tw, e, w1r, w1i);
        twget<-1>(tw, 2 * e, w2r, w2i);
        twget<-1>(tw, 3 * e, w3r, w3i);
        re[p1] = u1r * w1r - u1i * w1i; im[p1] = u1r * w1i + u1i * w1r;
        re[p2_] = u2r * w2r - u2i * w2i; im[p2_] = u2r * w2i + u2i * w2r;
        re[p3] = u3r * w3r - u3i * w3i; im[p3] = u3r * w3i + u3i * w3r;
      }
      __syncthreads();
    }
    // accumulate cross-spectrum into registers (position p holds Z[rev4(p)])
#pragma unroll
    for (int i = 0; i < 16; ++i) {
      const int p = tid + 256 * i;
      const int f = rev4_12(p);
      const int f2 = (LEN - f) & (LEN - 1);
      const int p2 = rev4_12(f2);
      const float ar = re[PAD(p)], ai = im[PAD(p)];
      const float br = re[PAD(p2)], bi = im[PAD(p2)];
      srg[i] += 0.5f * (ar * bi + ai * br);
      sig[i] += 0.25f * ((ar * ar + ai * ai) - (br * br + bi * bi));
    }
  }
  float2* op = part + (size_t)(bh * nb + g) * LEN;
#pragma unroll
  for (int i = 0; i < 16; ++i) {
    const int p = tid + 256 * i;
    op[p] = make_float2(srg[i], sig[i]);
  }
}

// ---------------------------------------------------------------------------
// Pass R: sum partial spectra -> spec[bh][p]. Grid NBH*16, fully coalesced.
// ---------------------------------------------------------------------------
__global__ __launch_bounds__(256) void ac_reduce(const float2* __restrict__ part,
                                                 float2* __restrict__ spec,
                                                 int ngrp) {
  const int bh = blockIdx.x >> 4;
  const int p = ((blockIdx.x & 15) << 8) | threadIdx.x;
  float accr = 0.f, acci = 0.f;
  for (int g = 0; g < ngrp; ++g) {
    const float2 v = part[((size_t)(bh * ngrp + g) << LOG2LEN) + p];
    accr += v.x; acci += v.y;
  }
  spec[((size_t)bh << LOG2LEN) + p] = make_float2(accr, acci);
}

// ---------------------------------------------------------------------------
// Pass B: per (b,h): inverse radix-4 DIT (digit-reversed in -> natural out),
// scale by 1/(L*Dh), write corr.
// ---------------------------------------------------------------------------
__global__ __launch_bounds__(256, 4) void ac_fft_inv(const float2* __restrict__ spec,
                                                     const float2* __restrict__ tw,
                                                     float* __restrict__ corr) {
  __shared__ float re[PAD_LEN], im[PAD_LEN];
  const int bh = blockIdx.x;
  const int tid = threadIdx.x;
  for (int p = tid; p < LEN; p += 256) {
    const float2 v = spec[((size_t)bh << LOG2LEN) + p];
    re[PAD(p)] = v.x; im[PAD(p)] = v.y;
  }
  __syncthreads();
  // inverse radix-4 DIT: quarter q4 = 1 .. 1024
  int tmul = LEN / 4;
  for (int q4 = 1; q4 <= LEN / 4; q4 <<= 2, tmul >>= 2) {
#pragma unroll 4
    for (int m = tid; m < LEN / 4; m += 256) {
      const int j = m & (q4 - 1);
      const int i0 = ((m & ~(q4 - 1)) << 2) | j;
      const int i1 = i0 + q4, i2 = i0 + 2 * q4, i3 = i0 + 3 * q4;
      const int p0 = PAD(i0), p1 = PAD(i1), p2_ = PAD(i2), p3 = PAD(i3);
      const int e = tmul * j;
      float w1r, w1i, w2r, w2i, w3r, w3i;
      twget<1>(tw, e, w1r, w1i);
      twget<1>(tw, 2 * e, w2r, w2i);
      twget<1>(tw, 3 * e, w3r, w3i);
      const float x0r = re[p0], x0i = im[p0];
      const float y1r = re[p1], y1i = im[p1];
      const float y2r = re[p2_], y2i = im[p2_];
      const float y3r = re[p3], y3i = im[p3];
      const float x1r = y1r * w1r - y1i * w1i, x1i = y1r * w1i + y1i * w1r;
      const float x2r = y2r * w2r - y2i * w2i, x2i = y2r * w2i + y2i * w2r;
      const float x3r = y3r * w3r - y3i * w3i, x3i = y3r * w3i + y3i * w3r;
      const float t0r = x0r + x2r, t0i = x0i + x2i;
      const float t1r = x0r - x2r, t1i = x0i - x2i;
      const float t2r = x1r + x3r, t2i = x1i + x3i;
      const float t3r = x1r - x3r, t3i = x1i - x3i;
      re[p0] = t0r + t2r; im[p0] = t0i + t2i;
      re[p2_] = t0r - t2r; im[p2_] = t0i - t2i;
      re[p1] = t1r - t3i; im[p1] = t1i + t3r;  // t1 + i*t3
      re[p3] = t1r + t3i; im[p3] = t1i - t3r;  // t1 - i*t3
    }
    __syncthreads();
  }
  const float scale = 1.0f / ((float)LEN * (float)DH);
  for (int t = tid; t < LEN; t += 256) corr[(size_t)bh * LEN + t] = re[PAD(t)] * scale;
}

// ---------------------------------------------------------------------------
// Pass C: per (b,h): top-8 of corr (8 serial max-reductions) + softmax.
// ---------------------------------------------------------------------------
__global__ __launch_bounds__(256) void ac_topk(const float* __restrict__ corr,
                                               float* __restrict__ attn,
                                               int* __restrict__ delays) {
  __shared__ float vals[LEN];
  __shared__ float rv[256];
  __shared__ int ri[256];
  __shared__ float selv[KTOP];
  __shared__ int seli[KTOP];
  const int bh = blockIdx.x, tid = threadIdx.x;
  for (int t = tid; t < LEN; t += 256) vals[t] = corr[(size_t)bh * LEN + t];
  __syncthreads();
  for (int kk = 0; kk < KTOP; ++kk) {
    float mv = -3.0e38f;
    int mi = 0;
    for (int t = tid; t < LEN; t += 256) {
      const float x = vals[t];
      if (x > mv) { mv = x; mi = t; }
    }
    rv[tid] = mv; ri[tid] = mi;
    __syncthreads();
    for (int s = 128; s > 0; s >>= 1) {
      if (tid < s) {
        if (rv[tid + s] > rv[tid]) { rv[tid] = rv[tid + s]; ri[tid] = ri[tid + s]; }
      }
      __syncthreads();
    }
    if (tid == 0) {
      selv[kk] = rv[0];
      seli[kk] = ri[0];
      vals[ri[0]] = -3.0e38f;
    }
    __syncthreads();
  }
  if (tid == 0) {
    const float mx = selv[0];
    float ex[KTOP];
    float sum = 0.f;
    for (int j = 0; j < KTOP; ++j) { ex[j] = expf(selv[j] - mx); sum += ex[j]; }
    const float inv = 1.0f / sum;
    for (int j = 0; j < KTOP; ++j) {
      attn[bh * KTOP + j] = ex[j] * inv;
      delays[bh * KTOP + j] = seli[j];
    }
  }
}

// ---------------------------------------------------------------------------
// Pass D: out[bh,t,d] = sum_j attn_j * v[bh,(t-delay_j) mod L, d], float4.
// ---------------------------------------------------------------------------
__global__ __launch_bounds__(256) void ac_gather(const float* __restrict__ v,
                                                 const float* __restrict__ attn,
                                                 const int* __restrict__ delays,
                                                 float* __restrict__ out) {
  const int bx = blockIdx.x;
  const int xcd = bx & 7;
  const int i = bx >> 3;
  const int bh = (xcd << 2) | (i & 3);
  const int chunk = i >> 2;
  const int tid = threadIdx.x;
  float aw[KTOP];
  int dl[KTOP];
#pragma unroll
  for (int j = 0; j < KTOP; ++j) {
    aw[j] = attn[bh * KTOP + j];
    dl[j] = delays[bh * KTOP + j];
  }
  const int e = chunk * 1024 + tid * 4;
  const int t = e >> 6;
  const int d = e & 63;
  const float* vb = v + (size_t)bh * LEN * DH;
  float4 acc = make_float4(0.f, 0.f, 0.f, 0.f);
#pragma unroll
  for (int j = 0; j < KTOP; ++j) {
    int src = t - dl[j];
    if (src < 0) src += LEN;
    const float4 vv = *reinterpret_cast<const float4*>(vb + (size_t)src * DH + d);
    acc.x += aw[j] * vv.x;
    acc.y += aw[j] * vv.y;
    acc.z += aw[j] * vv.z;
    acc.w += aw[j] * vv.w;
  }
  *reinterpret_cast<float4*>(out + (size_t)bh * LEN * DH + e) = acc;
}

extern "C" void kernel_launch(void* const* d_in, const int* in_sizes, int n_in,
                              void* d_out, int out_size, void* d_ws, size_t ws_size,
                              hipStream_t stream) {
  const float* q = (const float*)d_in[0];
  const float* k = (const float*)d_in[1];
  const float* v = (const float*)d_in[2];
  float* out = (float*)d_out;

  // ws layout: tw | zT (TR only) | part | spec | corr | attn | delays
  auto need = [](int dpb, bool tr) -> size_t {
    const int nb = DH / dpb;
    size_t b = (size_t)TW_N * 8;
    if (tr) b += ZT_ELEMS * 8;
    b += (size_t)NBH * nb * LEN * 8;   // part
    b += (size_t)NBH * LEN * 8;        // spec
    b += (size_t)CORR_ELEMS * 4;       // corr
    b += (size_t)NBH * KTOP * 8;       // attn + delays
    return b;
  };

  int dpb;
  bool tr;
  if (ws_size >= need(2, true))      { dpb = 2; tr = true; }
  else if (ws_size >= need(4, true)) { dpb = 4; tr = true; }
  else if (ws_size >= need(8, true)) { dpb = 8; tr = true; }
  else                               { dpb = 8; tr = false; }
  const int nb = DH / dpb;

  float2* tw = (float2*)d_ws;
  float2* zT = tw + TW_N;
  float2* part = tr ? (zT + ZT_ELEMS) : zT;
  float2* spec = part + (size_t)NBH * nb * LEN;
  float* corr = (float*)(spec + (size_t)NBH * LEN);
  float* attn = corr + CORR_ELEMS;
  int* delays = (int*)(attn + NBH * KTOP);

  ac_twinit<<<dim3((TW_N + 255) / 256), dim3(256), 0, stream>>>(tw);
  if (tr) {
    ac_transpose<<<dim3(NBH * 64), dim3(256), 0, stream>>>(q, k, zT);
    if (dpb == 2)
      ac_fft_fwd<2, true><<<dim3(NBH * 32), dim3(256), 0, stream>>>(q, k, zT, tw, part);
    else if (dpb == 4)
      ac_fft_fwd<4, true><<<dim3(NBH * 16), dim3(256), 0, stream>>>(q, k, zT, tw, part);
    else
      ac_fft_fwd<8, true><<<dim3(NBH * 8), dim3(256), 0, stream>>>(q, k, zT, tw, part);
  } else {
    ac_fft_fwd<8, false><<<dim3(NBH * 8), dim3(256), 0, stream>>>(q, k, zT, tw, part);
  }
  ac_reduce<<<dim3(NBH * 16), dim3(256), 0, stream>>>(part, spec, nb);
  ac_fft_inv<<<dim3(NBH), dim3(256), 0, stream>>>(spec, tw, corr);
  ac_topk<<<dim3(NBH), dim3(256), 0, stream>>>(corr, attn, delays);
  ac_gather<<<dim3(NBH * 256), dim3(256), 0, stream>>>(v, attn, delays, out);
}

// Round 4
// 143.028 us; speedup vs baseline: 2.1994x; 1.0430x over previous
//
#include <hip/hip_runtime.h>
#include <math.h>

#define LEN 4096
#define LOG2LEN 12
#define DH 64
#define NBH 32      // B*H
#define KTOP 8

#define ZT_ELEMS ((size_t)NBH * DH * LEN)   // float2 count (64 MB)
#define TW_N (LEN / 2)                      // 2048 float2 twiddles

// base-16 digit reversal of a 12-bit index (3 hex digits)
__device__ __forceinline__ int rev16_12(int x) {
  return ((x & 15) << 8) | (x & 240) | (x >> 8);
}

// twiddle fetch from global half-table tw[j] = (cos(2pi j/L), sin(2pi j/L));
// SIM = -1 forward, +1 inverse. e in [0, 4096).
template <int SIM>
__device__ __forceinline__ void twget(const float2* __restrict__ tw, int e,
                                      float& wr, float& wi) {
  const float2 t = tw[e & (TW_N - 1)];
  const float sgn = (e & TW_N) ? -1.0f : 1.0f;
  wr = sgn * t.x;
  wi = sgn * (float)SIM * t.y;
}

// ---------------- in-register complex helpers / 16-point DFT ----------------
struct cf { float r, i; };
__device__ __forceinline__ cf cadd(const cf a, const cf b) { return {a.r + b.r, a.i + b.i}; }
__device__ __forceinline__ cf csub(const cf a, const cf b) { return {a.r - b.r, a.i - b.i}; }
__device__ __forceinline__ cf cmul(const cf a, const float wr, const float wi) {
  return {a.r * wr - a.i * wi, a.r * wi + a.i * wr};
}
// multiply by W^(N/4): forward (-i), inverse (+i)
template <int S>
__device__ __forceinline__ cf cmuli(const cf a) {
  return (S < 0) ? cf{a.i, -a.r} : cf{-a.i, a.r};
}
// multiply by (c, S*s)
template <int S>
__device__ __forceinline__ cf twc(const cf a, const float c, const float s) {
  return cmul(a, c, (S < 0) ? -s : s);
}
template <int S>
__device__ __forceinline__ void r4(cf& a, cf& b, cf& c, cf& d) {
  const cf t0 = cadd(a, c), t1 = csub(a, c), t2 = cadd(b, d), t3 = csub(b, d);
  const cf j3 = cmuli<S>(t3);
  a = cadd(t0, t2); c = csub(t0, t2);
  b = cadd(t1, j3); d = csub(t1, j3);
}
// 16-point DFT, natural order in and out, compile-time twiddles.
template <int S>
__device__ __forceinline__ void dft16(cf* x) {
  r4<S>(x[0], x[4], x[8], x[12]);
  r4<S>(x[1], x[5], x[9], x[13]);
  r4<S>(x[2], x[6], x[10], x[14]);
  r4<S>(x[3], x[7], x[11], x[15]);
  const float C1 = 0.92387953251128675613f;  // cos(pi/8)
  const float S1 = 0.38268343236508977173f;  // sin(pi/8)
  const float R2 = 0.70710678118654752440f;
  // slot n2+4k1 *= W16^{n2*k1}
  x[5] = twc<S>(x[5], C1, S1);
  x[6] = twc<S>(x[6], R2, R2);
  x[7] = twc<S>(x[7], S1, C1);
  x[9] = twc<S>(x[9], R2, R2);
  x[10] = cmuli<S>(x[10]);
  x[11] = twc<S>(x[11], -R2, R2);
  x[13] = twc<S>(x[13], S1, C1);
  x[14] = twc<S>(x[14], -R2, R2);
  x[15] = twc<S>(x[15], -C1, -S1);
  r4<S>(x[0], x[1], x[2], x[3]);
  r4<S>(x[4], x[5], x[6], x[7]);
  r4<S>(x[8], x[9], x[10], x[11]);
  r4<S>(x[12], x[13], x[14], x[15]);
  // slot(4k1+k2) holds X[4k2+k1] -> transpose to natural order
  cf t;
  t = x[1]; x[1] = x[4]; x[4] = t;
  t = x[2]; x[2] = x[8]; x[8] = t;
  t = x[3]; x[3] = x[12]; x[12] = t;
  t = x[6]; x[6] = x[9]; x[9] = t;
  t = x[7]; x[7] = x[13]; x[13] = t;
  t = x[11]; x[11] = x[14]; x[14] = t;
}

// padded exchange layout: array a (=top digit), slot c in [0,256): a*272 + c
// (272 % 32 == 16 -> every exchange pattern is <=2-way conflicted = free)
#define XSTR 272

// ---------------------------------------------------------------------------
// twiddle table init (fallback path only; TR path fuses into transpose)
// ---------------------------------------------------------------------------
__global__ void ac_twinit(float2* __restrict__ tw) {
  const int j = blockIdx.x * 256 + threadIdx.x;
  if (j < TW_N) {
    float s, c;
    sincosf(6.2831853071795864769f * (float)j / (float)LEN, &s, &c);
    tw[j] = make_float2(c, s);
  }
}

// ---------------------------------------------------------------------------
// Pass T: transpose q,k (bh,t,d) -> packed complex zT[(bh*64+d)*LEN + t],
// z = q + i*k. Coalesced both sides via padded LDS tiles. First 8 blocks also
// populate the twiddle table (2048 entries).
// ---------------------------------------------------------------------------
__global__ __launch_bounds__(256, 4) void ac_transpose(const float* __restrict__ q,
                                                       const float* __restrict__ k,
                                                       float2* __restrict__ zT,
                                                       float2* __restrict__ tw) {
  if (blockIdx.x < 8) {
    const int j = blockIdx.x * 256 + threadIdx.x;
    float s, c;
    sincosf(6.2831853071795864769f * (float)j / (float)LEN, &s, &c);
    tw[j] = make_float2(c, s);
  }
  __shared__ float tq[64][65], tk[64][65];
  const int bh = blockIdx.x >> 6;
  const int t0 = (blockIdx.x & 63) * 64;
  const int tid = threadIdx.x;
  const int tl = tid >> 2;
  const int c = tid & 3;
  const float* qb = q + ((size_t)bh * LEN + t0) * DH;
  const float* kb = k + ((size_t)bh * LEN + t0) * DH;
#pragma unroll
  for (int r = 0; r < 4; ++r) {
    const int d0 = (c + r * 4) * 4;
    const float4 vq = *reinterpret_cast<const float4*>(qb + (size_t)tl * DH + d0);
    const float4 vk = *reinterpret_cast<const float4*>(kb + (size_t)tl * DH + d0);
    tq[tl][d0] = vq.x; tq[tl][d0 + 1] = vq.y; tq[tl][d0 + 2] = vq.z; tq[tl][d0 + 3] = vq.w;
    tk[tl][d0] = vk.x; tk[tl][d0 + 1] = vk.y; tk[tl][d0 + 2] = vk.z; tk[tl][d0 + 3] = vk.w;
  }
  __syncthreads();
  const int d = tid >> 2;
  const int s = tid & 3;
  float2* ob = zT + ((size_t)(bh * DH + d)) * LEN + t0;
#pragma unroll
  for (int r = 0; r < 8; ++r) {
    const int t = (s + r * 4) * 2;
    const float4 o = make_float4(tq[t][d], tk[t][d], tq[t + 1][d], tk[t + 1][d]);
    *reinterpret_cast<float4*>(&ob[t]) = o;
  }
}

// ---------------------------------------------------------------------------
// Pass A: forward FFT of z = q_d + i*k_d as 16x16x16: three in-register
// 16-pt DFTs + 2 LDS exchanges. Output position p holds Z[rev16(p)].
// Cross-spectrum P[f] = Q conj(K) = Im(A*B)/2 + i(|A|^2-|B|^2)/4, A=Z[f],
// B=Z[-f], accumulated in registers across DPB d's; partials digit-reversed.
// ---------------------------------------------------------------------------
template <int DPB, bool TR>
__global__ __launch_bounds__(256, 4) void ac_fft_fwd(const float* __restrict__ q,
                                                     const float* __restrict__ k,
                                                     const float2* __restrict__ zT,
                                                     const float2* __restrict__ tw,
                                                     float2* __restrict__ part) {
  __shared__ float lre[16 * XSTR], lim[16 * XSTR];  // 34.8 KB
  const int nb = DH / DPB;
  const int bh = blockIdx.x / nb;
  const int g = blockIdx.x % nb;
  const int tid = threadIdx.x;
  const int hi = tid >> 4, lo = tid & 15;

  float srg[16], sig[16];
#pragma unroll
  for (int i = 0; i < 16; ++i) { srg[i] = 0.f; sig[i] = 0.f; }

  for (int dd = 0; dd < DPB; ++dd) {
    const int d = g * DPB + dd;
    cf x[16];
    if (TR) {
      const float2* zb = zT + (size_t)(bh * DH + d) * LEN;
#pragma unroll
      for (int n1 = 0; n1 < 16; ++n1) {
        const float2 z = zb[tid + 256 * n1];
        x[n1].r = z.x; x[n1].i = z.y;
      }
    } else {
      const float* qb = q + (size_t)bh * LEN * DH + d;
      const float* kb = k + (size_t)bh * LEN * DH + d;
#pragma unroll
      for (int n1 = 0; n1 < 16; ++n1) {
        x[n1].r = qb[(size_t)(tid + 256 * n1) * DH];
        x[n1].i = kb[(size_t)(tid + 256 * n1) * DH];
      }
    }
    // stage 1: DFT over n1 (stride 256), twiddle W4096^{n2*k1}, n2 = tid
    dft16<-1>(x);
#pragma unroll
    for (int k1 = 1; k1 < 16; ++k1) {
      float wr, wi;
      twget<-1>(tw, tid * k1, wr, wi);
      x[k1] = cmul(x[k1], wr, wi);
    }
    __syncthreads();  // previous iteration's pair-reads complete
#pragma unroll
    for (int k1 = 0; k1 < 16; ++k1) {
      lre[k1 * XSTR + tid] = x[k1].r;
      lim[k1 * XSTR + tid] = x[k1].i;
    }
    __syncthreads();
    // stage 2 inputs: fixed (k1=hi, m2=lo), over m1
#pragma unroll
    for (int m1 = 0; m1 < 16; ++m1) {
      const int a = hi * XSTR + 16 * m1 + lo;
      x[m1].r = lre[a]; x[m1].i = lim[a];
    }
    dft16<-1>(x);
#pragma unroll
    for (int j1 = 1; j1 < 16; ++j1) {  // twiddle W256^{m2*j1} = W4096^{16*lo*j1}
      float wr, wi;
      twget<-1>(tw, 16 * lo * j1, wr, wi);
      x[j1] = cmul(x[j1], wr, wi);
    }
    __syncthreads();  // all stage-2 reads done
#pragma unroll
    for (int j1 = 0; j1 < 16; ++j1) {
      lre[hi * XSTR + 16 * j1 + lo] = x[j1].r;
      lim[hi * XSTR + 16 * j1 + lo] = x[j1].i;
    }
    __syncthreads();
    // stage 3 inputs: fixed (k1=hi, j1=lo), over m2 (contiguous 16)
#pragma unroll
    for (int m2 = 0; m2 < 16; ++m2) {
      const int a = hi * XSTR + 16 * lo + m2;
      x[m2].r = lre[a]; x[m2].i = lim[a];
    }
    dft16<-1>(x);
    __syncthreads();  // all stage-3 reads done
#pragma unroll
    for (int j2 = 0; j2 < 16; ++j2) {  // p = 256*hi + 16*lo + j2
      lre[hi * XSTR + 16 * lo + j2] = x[j2].r;
      lim[hi * XSTR + 16 * lo + j2] = x[j2].i;
    }
    __syncthreads();
    // cross-spectrum pairing: position p holds Z[rev16(p)]
#pragma unroll
    for (int i = 0; i < 16; ++i) {
      const int p = tid + 256 * i;
      const int f = rev16_12(p);
      const int f2 = (LEN - f) & (LEN - 1);
      const int p2 = rev16_12(f2);
      const int a1 = i * XSTR + tid;
      const int a2 = (p2 >> 8) * XSTR + (p2 & 255);
      const float ar = lre[a1], ai = lim[a1];
      const float br = lre[a2], bi = lim[a2];
      srg[i] += 0.5f * (ar * bi + ai * br);
      sig[i] += 0.25f * ((ar * ar + ai * ai) - (br * br + bi * bi));
    }
  }
  float2* op = part + (size_t)(bh * nb + g) * LEN;
#pragma unroll
  for (int i = 0; i < 16; ++i) op[tid + 256 * i] = make_float2(srg[i], sig[i]);
}

// ---------------------------------------------------------------------------
// Pass R: sum partial spectra -> spec[bh][p]. Grid NBH*16, fully coalesced.
// ---------------------------------------------------------------------------
__global__ __launch_bounds__(256) void ac_reduce(const float2* __restrict__ part,
                                                 float2* __restrict__ spec,
                                                 int ngrp) {
  const int bh = blockIdx.x >> 4;
  const int p = ((blockIdx.x & 15) << 8) | threadIdx.x;
  float accr = 0.f, acci = 0.f;
  for (int g = 0; g < ngrp; ++g) {
    const float2 v = part[((size_t)(bh * ngrp + g) << LOG2LEN) + p];
    accr += v.x; acci += v.y;
  }
  spec[((size_t)bh << LOG2LEN) + p] = make_float2(accr, acci);
}

// ---------------------------------------------------------------------------
// Pass B+C: per (b,h): inverse FFT 16x16x16 (digit-reversed in -> natural
// out) fused with top-8 + softmax. Writes attn + delays only.
// ---------------------------------------------------------------------------
__global__ __launch_bounds__(256, 4) void ac_fft_inv(const float2* __restrict__ spec,
                                                     const float2* __restrict__ tw,
                                                     float* __restrict__ attn,
                                                     int* __restrict__ delays) {
  __shared__ float lre[16 * XSTR], lim[16 * XSTR];
  __shared__ float rv[256];
  __shared__ int ri[256];
  __shared__ float selv[KTOP];
  __shared__ int seli[KTOP];
  const int bh = blockIdx.x;
  const int tid = threadIdx.x;
  const int hi = tid >> 4, lo = tid & 15;
  const float2* sp = spec + ((size_t)bh << LOG2LEN);

  // input: position p = 16*tid + f2 holds P[rev16(p)]; thread = (f0=hi, f1=lo)
  cf x[16];
#pragma unroll
  for (int f2 = 0; f2 < 16; ++f2) {
    const float2 z = sp[16 * tid + f2];
    x[f2].r = z.x; x[f2].i = z.y;
  }
  // stage A: DFT over f2 -> A1[t0]; twiddle W4096^{16*f1*t0}
  dft16<1>(x);
#pragma unroll
  for (int t0 = 1; t0 < 16; ++t0) {
    float wr, wi;
    twget<1>(tw, 16 * lo * t0, wr, wi);
    x[t0] = cmul(x[t0], wr, wi);
  }
#pragma unroll
  for (int t0 = 0; t0 < 16; ++t0) {
    lre[hi * XSTR + 16 * t0 + lo] = x[t0].r;
    lim[hi * XSTR + 16 * t0 + lo] = x[t0].i;
  }
  __syncthreads();
  // stage B: thread (f0=hi, t0=lo), over f1 (contiguous)
#pragma unroll
  for (int f1 = 0; f1 < 16; ++f1) {
    const int a = hi * XSTR + 16 * lo + f1;
    x[f1].r = lre[a]; x[f1].i = lim[a];
  }
  dft16<1>(x);
#pragma unroll
  for (int t1 = 0; t1 < 16; ++t1) {  // twiddle W4096^{f0*(16*t1+t0)}
    float wr, wi;
    twget<1>(tw, hi * (16 * t1 + lo), wr, wi);
    x[t1] = cmul(x[t1], wr, wi);
  }
  __syncthreads();  // stage-B reads done
#pragma unroll
  for (int t1 = 0; t1 < 16; ++t1) {
    lre[hi * XSTR + 16 * t1 + lo] = x[t1].r;
    lim[hi * XSTR + 16 * t1 + lo] = x[t1].i;
  }
  __syncthreads();
  // stage C: thread (t1=hi, t0=lo), over f0 (stride XSTR)
#pragma unroll
  for (int f0 = 0; f0 < 16; ++f0) {
    const int a = f0 * XSTR + 16 * hi + lo;
    x[f0].r = lre[a]; x[f0].i = lim[a];
  }
  dft16<1>(x);
  __syncthreads();  // stage-C reads done; reuse lre as vals[4096]
  const float scale = 1.0f / ((float)LEN * (float)DH);
#pragma unroll
  for (int t2 = 0; t2 < 16; ++t2) lre[256 * t2 + tid] = x[t2].r * scale;  // t = 256*t2 + tid
  __syncthreads();

  // top-8 + softmax on vals = lre[0..4095]
  for (int kk = 0; kk < KTOP; ++kk) {
    float mv = -3.0e38f;
    int mi = 0;
    for (int t = tid; t < LEN; t += 256) {
      const float xv = lre[t];
      if (xv > mv) { mv = xv; mi = t; }
    }
    rv[tid] = mv; ri[tid] = mi;
    __syncthreads();
    for (int s = 128; s > 0; s >>= 1) {
      if (tid < s) {
        if (rv[tid + s] > rv[tid]) { rv[tid] = rv[tid + s]; ri[tid] = ri[tid + s]; }
      }
      __syncthreads();
    }
    if (tid == 0) {
      selv[kk] = rv[0];
      seli[kk] = ri[0];
      lre[ri[0]] = -3.0e38f;
    }
    __syncthreads();
  }
  if (tid == 0) {
    const float mx = selv[0];
    float ex[KTOP];
    float sum = 0.f;
    for (int j = 0; j < KTOP; ++j) { ex[j] = expf(selv[j] - mx); sum += ex[j]; }
    const float inv = 1.0f / sum;
    for (int j = 0; j < KTOP; ++j) {
      attn[bh * KTOP + j] = ex[j] * inv;
      delays[bh * KTOP + j] = seli[j];
    }
  }
}

// ---------------------------------------------------------------------------
// Pass D: out[bh,t,d] = sum_j attn_j * v[bh,(t-delay_j) mod L, d], float4.
// ---------------------------------------------------------------------------
__global__ __launch_bounds__(256) void ac_gather(const float* __restrict__ v,
                                                 const float* __restrict__ attn,
                                                 const int* __restrict__ delays,
                                                 float* __restrict__ out) {
  const int bx = blockIdx.x;
  const int xcd = bx & 7;
  const int i = bx >> 3;
  const int bh = (xcd << 2) | (i & 3);
  const int chunk = i >> 2;
  const int tid = threadIdx.x;
  float aw[KTOP];
  int dl[KTOP];
#pragma unroll
  for (int j = 0; j < KTOP; ++j) {
    aw[j] = attn[bh * KTOP + j];
    dl[j] = delays[bh * KTOP + j];
  }
  const int e = chunk * 1024 + tid * 4;
  const int t = e >> 6;
  const int d = e & 63;
  const float* vb = v + (size_t)bh * LEN * DH;
  float4 acc = make_float4(0.f, 0.f, 0.f, 0.f);
#pragma unroll
  for (int j = 0; j < KTOP; ++j) {
    int src = t - dl[j];
    if (src < 0) src += LEN;
    const float4 vv = *reinterpret_cast<const float4*>(vb + (size_t)src * DH + d);
    acc.x += aw[j] * vv.x;
    acc.y += aw[j] * vv.y;
    acc.z += aw[j] * vv.z;
    acc.w += aw[j] * vv.w;
  }
  *reinterpret_cast<float4*>(out + (size_t)bh * LEN * DH + e) = acc;
}

extern "C" void kernel_launch(void* const* d_in, const int* in_sizes, int n_in,
                              void* d_out, int out_size, void* d_ws, size_t ws_size,
                              hipStream_t stream) {
  const float* q = (const float*)d_in[0];
  const float* k = (const float*)d_in[1];
  const float* v = (const float*)d_in[2];
  float* out = (float*)d_out;

  // ws layout: tw | zT (TR only) | part | spec | attn | delays
  auto need = [](int dpb, bool tr) -> size_t {
    const int nb = DH / dpb;
    size_t b = (size_t)TW_N * 8;
    if (tr) b += ZT_ELEMS * 8;
    b += (size_t)NBH * nb * LEN * 8;  // part
    b += (size_t)NBH * LEN * 8;       // spec
    b += (size_t)NBH * KTOP * 8;      // attn + delays
    return b;
  };

  int dpb;
  bool tr;
  if (ws_size >= need(2, true))      { dpb = 2; tr = true; }
  else if (ws_size >= need(4, true)) { dpb = 4; tr = true; }
  else if (ws_size >= need(8, true)) { dpb = 8; tr = true; }
  else                               { dpb = 8; tr = false; }
  const int nb = DH / dpb;

  float2* tw = (float2*)d_ws;
  float2* zT = tw + TW_N;
  float2* part = tr ? (zT + ZT_ELEMS) : zT;
  float2* spec = part + (size_t)NBH * nb * LEN;
  float* attn = (float*)(spec + (size_t)NBH * LEN);
  int* delays = (int*)(attn + NBH * KTOP);

  if (tr) {
    ac_transpose<<<dim3(NBH * 64), dim3(256), 0, stream>>>(q, k, zT, tw);
    if (dpb == 2)
      ac_fft_fwd<2, true><<<dim3(NBH * 32), dim3(256), 0, stream>>>(q, k, zT, tw, part);
    else if (dpb == 4)
      ac_fft_fwd<4, true><<<dim3(NBH * 16), dim3(256), 0, stream>>>(q, k, zT, tw, part);
    else
      ac_fft_fwd<8, true><<<dim3(NBH * 8), dim3(256), 0, stream>>>(q, k, zT, tw, part);
  } else {
    ac_twinit<<<dim3((TW_N + 255) / 256), dim3(256), 0, stream>>>(tw);
    ac_fft_fwd<8, false><<<dim3(NBH * 8), dim3(256), 0, stream>>>(q, k, zT, tw, part);
  }
  ac_reduce<<<dim3(NBH * 16), dim3(256), 0, stream>>>(part, spec, nb);
  ac_fft_inv<<<dim3(NBH), dim3(256), 0, stream>>>(spec, tw, attn, delays);
  ac_gather<<<dim3(NBH * 256), dim3(256), 0, stream>>>(v, attn, delays, out);
}

// Round 5
// 108.620 us; speedup vs baseline: 2.8962x; 1.3168x over previous
//
#include <hip/hip_runtime.h>
#include <math.h>

#define LEN 4096
#define LOG2LEN 12
#define DH 64
#define NBH 32      // B*H
#define KTOP 8

#define ZT_ELEMS ((size_t)NBH * DH * LEN)   // float2 count (67 MB)
#define TW_N (LEN / 2)                      // 2048 float2 twiddles

// base-16 digit reversal of a 12-bit index (3 hex digits)
__device__ __forceinline__ int rev16_12(int x) {
  return ((x & 15) << 8) | (x & 240) | (x >> 8);
}

// twiddle fetch from global half-table tw[j] = (cos(2pi j/L), sin(2pi j/L));
// SIM = -1 forward, +1 inverse. e in [0, 4096).
template <int SIM>
__device__ __forceinline__ void twget(const float2* __restrict__ tw, int e,
                                      float& wr, float& wi) {
  const float2 t = tw[e & (TW_N - 1)];
  const float sgn = (e & TW_N) ? -1.0f : 1.0f;
  wr = sgn * t.x;
  wi = sgn * (float)SIM * t.y;
}

// ---------------- in-register complex helpers / 16-point DFT ----------------
struct cf { float r, i; };
__device__ __forceinline__ cf cadd(const cf a, const cf b) { return {a.r + b.r, a.i + b.i}; }
__device__ __forceinline__ cf csub(const cf a, const cf b) { return {a.r - b.r, a.i - b.i}; }
__device__ __forceinline__ cf cmul(const cf a, const float wr, const float wi) {
  return {a.r * wr - a.i * wi, a.r * wi + a.i * wr};
}
// multiply by W^(N/4): forward (-i), inverse (+i)
template <int S>
__device__ __forceinline__ cf cmuli(const cf a) {
  return (S < 0) ? cf{a.i, -a.r} : cf{-a.i, a.r};
}
// multiply by (c, S*s)
template <int S>
__device__ __forceinline__ cf twc(const cf a, const float c, const float s) {
  return cmul(a, c, (S < 0) ? -s : s);
}
template <int S>
__device__ __forceinline__ void r4(cf& a, cf& b, cf& c, cf& d) {
  const cf t0 = cadd(a, c), t1 = csub(a, c), t2 = cadd(b, d), t3 = csub(b, d);
  const cf j3 = cmuli<S>(t3);
  a = cadd(t0, t2); c = csub(t0, t2);
  b = cadd(t1, j3); d = csub(t1, j3);
}
// 16-point DFT, natural order in and out, compile-time twiddles.
template <int S>
__device__ __forceinline__ void dft16(cf* x) {
  r4<S>(x[0], x[4], x[8], x[12]);
  r4<S>(x[1], x[5], x[9], x[13]);
  r4<S>(x[2], x[6], x[10], x[14]);
  r4<S>(x[3], x[7], x[11], x[15]);
  const float C1 = 0.92387953251128675613f;  // cos(pi/8)
  const float S1 = 0.38268343236508977173f;  // sin(pi/8)
  const float R2 = 0.70710678118654752440f;
  // slot n2+4k1 *= W16^{n2*k1}
  x[5] = twc<S>(x[5], C1, S1);
  x[6] = twc<S>(x[6], R2, R2);
  x[7] = twc<S>(x[7], S1, C1);
  x[9] = twc<S>(x[9], R2, R2);
  x[10] = cmuli<S>(x[10]);
  x[11] = twc<S>(x[11], -R2, R2);
  x[13] = twc<S>(x[13], S1, C1);
  x[14] = twc<S>(x[14], -R2, R2);
  x[15] = twc<S>(x[15], -C1, -S1);
  r4<S>(x[0], x[1], x[2], x[3]);
  r4<S>(x[4], x[5], x[6], x[7]);
  r4<S>(x[8], x[9], x[10], x[11]);
  r4<S>(x[12], x[13], x[14], x[15]);
  // slot(4k1+k2) holds X[4k2+k1] -> transpose to natural order
  cf t;
  t = x[1]; x[1] = x[4]; x[4] = t;
  t = x[2]; x[2] = x[8]; x[8] = t;
  t = x[3]; x[3] = x[12]; x[12] = t;
  t = x[6]; x[6] = x[9]; x[9] = t;
  t = x[7]; x[7] = x[13]; x[13] = t;
  t = x[11]; x[11] = x[14]; x[14] = t;
}

// padded exchange layout: array a (=top digit), slot c in [0,256): a*272 + c
// (272 % 32 == 16 -> every exchange pattern is <=2-way conflicted = free)
#define XSTR 272

// ---------------------------------------------------------------------------
// twiddle table init (fallback path only; TR path fuses into transpose)
// ---------------------------------------------------------------------------
__global__ void ac_twinit(float2* __restrict__ tw) {
  const int j = blockIdx.x * 256 + threadIdx.x;
  if (j < TW_N) {
    float s, c;
    sincosf(6.2831853071795864769f * (float)j / (float)LEN, &s, &c);
    tw[j] = make_float2(c, s);
  }
}

// ---------------------------------------------------------------------------
// Pass T: transpose q,k (bh,t,d) -> packed complex zT[(bh*64+d)*LEN + t],
// z = q + i*k. Coalesced both sides via padded LDS tiles. First 8 blocks also
// populate the twiddle table (2048 entries).
// ---------------------------------------------------------------------------
__global__ __launch_bounds__(256, 4) void ac_transpose(const float* __restrict__ q,
                                                       const float* __restrict__ k,
                                                       float2* __restrict__ zT,
                                                       float2* __restrict__ tw) {
  if (blockIdx.x < 8) {
    const int j = blockIdx.x * 256 + threadIdx.x;
    float s, c;
    sincosf(6.2831853071795864769f * (float)j / (float)LEN, &s, &c);
    tw[j] = make_float2(c, s);
  }
  __shared__ float tq[64][65], tk[64][65];
  const int bh = blockIdx.x >> 6;
  const int t0 = (blockIdx.x & 63) * 64;
  const int tid = threadIdx.x;
  const int tl = tid >> 2;
  const int c = tid & 3;
  const float* qb = q + ((size_t)bh * LEN + t0) * DH;
  const float* kb = k + ((size_t)bh * LEN + t0) * DH;
#pragma unroll
  for (int r = 0; r < 4; ++r) {
    const int d0 = (c + r * 4) * 4;
    const float4 vq = *reinterpret_cast<const float4*>(qb + (size_t)tl * DH + d0);
    const float4 vk = *reinterpret_cast<const float4*>(kb + (size_t)tl * DH + d0);
    tq[tl][d0] = vq.x; tq[tl][d0 + 1] = vq.y; tq[tl][d0 + 2] = vq.z; tq[tl][d0 + 3] = vq.w;
    tk[tl][d0] = vk.x; tk[tl][d0 + 1] = vk.y; tk[tl][d0 + 2] = vk.z; tk[tl][d0 + 3] = vk.w;
  }
  __syncthreads();
  const int d = tid >> 2;
  const int s = tid & 3;
  float2* ob = zT + ((size_t)(bh * DH + d)) * LEN + t0;
#pragma unroll
  for (int r = 0; r < 8; ++r) {
    const int t = (s + r * 4) * 2;
    const float4 o = make_float4(tq[t][d], tk[t][d], tq[t + 1][d], tk[t + 1][d]);
    *reinterpret_cast<float4*>(&ob[t]) = o;
  }
}

// ---------------------------------------------------------------------------
// Pass A: one block per (bh,d) slab. Forward FFT of z = q_d + i*k_d as
// 16x16x16 (three in-register 16-pt DFTs + 2 LDS exchanges); output position
// p holds Z[rev16(p)]. Cross-spectrum P[f] = Q conj(K) = Im(A*B)/2 +
// i(|A|^2-|B|^2)/4 (A=Z[f], B=Z[-f]) computed from LDS and written DIRECTLY
// back over the block's own input slab (read fully before write -> race-free,
// zero extra workspace, no register accumulators, no spills).
// ---------------------------------------------------------------------------
template <bool TR>
__global__ __launch_bounds__(256, 4) void ac_fft_fwd(const float* __restrict__ q,
                                                     const float* __restrict__ k,
                                                     const float2* __restrict__ zin,
                                                     const float2* __restrict__ tw,
                                                     float2* __restrict__ pout) {
  __shared__ float lre[16 * XSTR], lim[16 * XSTR];  // 34.8 KB
  const int tid = threadIdx.x;
  const int hi = tid >> 4, lo = tid & 15;
  const size_t slab = (size_t)blockIdx.x * LEN;  // blockIdx.x = bh*64 + d

  cf x[16];
  if (TR) {
    const float2* zb = zin + slab;
#pragma unroll
    for (int n1 = 0; n1 < 16; ++n1) {
      const float2 z = zb[tid + 256 * n1];
      x[n1].r = z.x; x[n1].i = z.y;
    }
  } else {
    const int bh = blockIdx.x >> 6;
    const int d = blockIdx.x & 63;
    const float* qb = q + (size_t)bh * LEN * DH + d;
    const float* kb = k + (size_t)bh * LEN * DH + d;
#pragma unroll
    for (int n1 = 0; n1 < 16; ++n1) {
      x[n1].r = qb[(size_t)(tid + 256 * n1) * DH];
      x[n1].i = kb[(size_t)(tid + 256 * n1) * DH];
    }
  }
  // stage 1: DFT over n1 (stride 256), twiddle W4096^{n2*k1}, n2 = tid
  dft16<-1>(x);
#pragma unroll
  for (int k1 = 1; k1 < 16; ++k1) {
    float wr, wi;
    twget<-1>(tw, tid * k1, wr, wi);
    x[k1] = cmul(x[k1], wr, wi);
  }
#pragma unroll
  for (int k1 = 0; k1 < 16; ++k1) {
    lre[k1 * XSTR + tid] = x[k1].r;
    lim[k1 * XSTR + tid] = x[k1].i;
  }
  __syncthreads();
  // stage 2 inputs: fixed (k1=hi, m2=lo), over m1
#pragma unroll
  for (int m1 = 0; m1 < 16; ++m1) {
    const int a = hi * XSTR + 16 * m1 + lo;
    x[m1].r = lre[a]; x[m1].i = lim[a];
  }
  dft16<-1>(x);
#pragma unroll
  for (int j1 = 1; j1 < 16; ++j1) {  // twiddle W256^{m2*j1} = W4096^{16*lo*j1}
    float wr, wi;
    twget<-1>(tw, 16 * lo * j1, wr, wi);
    x[j1] = cmul(x[j1], wr, wi);
  }
  __syncthreads();  // all stage-2 reads done
#pragma unroll
  for (int j1 = 0; j1 < 16; ++j1) {
    lre[hi * XSTR + 16 * j1 + lo] = x[j1].r;
    lim[hi * XSTR + 16 * j1 + lo] = x[j1].i;
  }
  __syncthreads();
  // stage 3 inputs: fixed (k1=hi, j1=lo), over m2 (contiguous 16)
#pragma unroll
  for (int m2 = 0; m2 < 16; ++m2) {
    const int a = hi * XSTR + 16 * lo + m2;
    x[m2].r = lre[a]; x[m2].i = lim[a];
  }
  dft16<-1>(x);
  __syncthreads();  // all stage-3 reads done
#pragma unroll
  for (int j2 = 0; j2 < 16; ++j2) {  // p = 256*hi + 16*lo + j2
    lre[hi * XSTR + 16 * lo + j2] = x[j2].r;
    lim[hi * XSTR + 16 * lo + j2] = x[j2].i;
  }
  __syncthreads();
  // cross-spectrum pairing (position p holds Z[rev16(p)]); write straight out
  float2* op = pout + slab;
#pragma unroll
  for (int i = 0; i < 16; ++i) {
    const int p = tid + 256 * i;
    const int f = rev16_12(p);
    const int f2 = (LEN - f) & (LEN - 1);
    const int p2 = rev16_12(f2);
    const int a1 = i * XSTR + tid;
    const int a2 = (p2 >> 8) * XSTR + (p2 & 255);
    const float ar = lre[a1], ai = lim[a1];
    const float br = lre[a2], bi = lim[a2];
    op[p] = make_float2(0.5f * (ar * bi + ai * br),
                        0.25f * ((ar * ar + ai * ai) - (br * br + bi * bi)));
  }
}

// ---------------------------------------------------------------------------
// Pass R: sum 64 partial spectra -> spec[bh][p]. Grid NBH*16, coalesced.
// ---------------------------------------------------------------------------
__global__ __launch_bounds__(256) void ac_reduce(const float2* __restrict__ part,
                                                 float2* __restrict__ spec) {
  const int bh = blockIdx.x >> 4;
  const int p = ((blockIdx.x & 15) << 8) | threadIdx.x;
  float accr = 0.f, acci = 0.f;
#pragma unroll 8
  for (int g = 0; g < DH; ++g) {
    const float2 v = part[((size_t)(bh * DH + g) << LOG2LEN) + p];
    accr += v.x; acci += v.y;
  }
  spec[((size_t)bh << LOG2LEN) + p] = make_float2(accr, acci);
}

// ---------------------------------------------------------------------------
// Pass B+C: per (b,h): inverse FFT 16x16x16 (digit-reversed in -> natural
// out) fused with top-8 + softmax. Writes attn + delays only.
// ---------------------------------------------------------------------------
__global__ __launch_bounds__(256, 4) void ac_fft_inv(const float2* __restrict__ spec,
                                                     const float2* __restrict__ tw,
                                                     float* __restrict__ attn,
                                                     int* __restrict__ delays) {
  __shared__ float lre[16 * XSTR], lim[16 * XSTR];
  __shared__ float rv[256];
  __shared__ int ri[256];
  __shared__ float selv[KTOP];
  __shared__ int seli[KTOP];
  const int bh = blockIdx.x;
  const int tid = threadIdx.x;
  const int hi = tid >> 4, lo = tid & 15;
  const float2* sp = spec + ((size_t)bh << LOG2LEN);

  // input: position p = 16*tid + f2 holds P[rev16(p)]; thread = (f0=hi, f1=lo)
  cf x[16];
#pragma unroll
  for (int f2 = 0; f2 < 16; ++f2) {
    const float2 z = sp[16 * tid + f2];
    x[f2].r = z.x; x[f2].i = z.y;
  }
  // stage A: DFT over f2 -> A1[t0]; twiddle W4096^{16*f1*t0}
  dft16<1>(x);
#pragma unroll
  for (int t0 = 1; t0 < 16; ++t0) {
    float wr, wi;
    twget<1>(tw, 16 * lo * t0, wr, wi);
    x[t0] = cmul(x[t0], wr, wi);
  }
#pragma unroll
  for (int t0 = 0; t0 < 16; ++t0) {
    lre[hi * XSTR + 16 * t0 + lo] = x[t0].r;
    lim[hi * XSTR + 16 * t0 + lo] = x[t0].i;
  }
  __syncthreads();
  // stage B: thread (f0=hi, t0=lo), over f1 (contiguous)
#pragma unroll
  for (int f1 = 0; f1 < 16; ++f1) {
    const int a = hi * XSTR + 16 * lo + f1;
    x[f1].r = lre[a]; x[f1].i = lim[a];
  }
  dft16<1>(x);
#pragma unroll
  for (int t1 = 0; t1 < 16; ++t1) {  // twiddle W4096^{f0*(16*t1+t0)}
    float wr, wi;
    twget<1>(tw, hi * (16 * t1 + lo), wr, wi);
    x[t1] = cmul(x[t1], wr, wi);
  }
  __syncthreads();  // stage-B reads done
#pragma unroll
  for (int t1 = 0; t1 < 16; ++t1) {
    lre[hi * XSTR + 16 * t1 + lo] = x[t1].r;
    lim[hi * XSTR + 16 * t1 + lo] = x[t1].i;
  }
  __syncthreads();
  // stage C: thread (t1=hi, t0=lo), over f0 (stride XSTR)
#pragma unroll
  for (int f0 = 0; f0 < 16; ++f0) {
    const int a = f0 * XSTR + 16 * hi + lo;
    x[f0].r = lre[a]; x[f0].i = lim[a];
  }
  dft16<1>(x);
  __syncthreads();  // stage-C reads done; reuse lre as vals[4096]
  const float scale = 1.0f / ((float)LEN * (float)DH);
#pragma unroll
  for (int t2 = 0; t2 < 16; ++t2) lre[256 * t2 + tid] = x[t2].r * scale;  // t = 256*t2 + tid
  __syncthreads();

  // top-8 + softmax on vals = lre[0..4095]
  for (int kk = 0; kk < KTOP; ++kk) {
    float mv = -3.0e38f;
    int mi = 0;
    for (int t = tid; t < LEN; t += 256) {
      const float xv = lre[t];
      if (xv > mv) { mv = xv; mi = t; }
    }
    rv[tid] = mv; ri[tid] = mi;
    __syncthreads();
    for (int s = 128; s > 0; s >>= 1) {
      if (tid < s) {
        if (rv[tid + s] > rv[tid]) { rv[tid] = rv[tid + s]; ri[tid] = ri[tid + s]; }
      }
      __syncthreads();
    }
    if (tid == 0) {
      selv[kk] = rv[0];
      seli[kk] = ri[0];
      lre[ri[0]] = -3.0e38f;
    }
    __syncthreads();
  }
  if (tid == 0) {
    const float mx = selv[0];
    float ex[KTOP];
    float sum = 0.f;
    for (int j = 0; j < KTOP; ++j) { ex[j] = expf(selv[j] - mx); sum += ex[j]; }
    const float inv = 1.0f / sum;
    for (int j = 0; j < KTOP; ++j) {
      attn[bh * KTOP + j] = ex[j] * inv;
      delays[bh * KTOP + j] = seli[j];
    }
  }
}

// ---------------------------------------------------------------------------
// Pass D: out[bh,t,d] = sum_j attn_j * v[bh,(t-delay_j) mod L, d], float4.
// ---------------------------------------------------------------------------
__global__ __launch_bounds__(256) void ac_gather(const float* __restrict__ v,
                                                 const float* __restrict__ attn,
                                                 const int* __restrict__ delays,
                                                 float* __restrict__ out) {
  const int bx = blockIdx.x;
  const int xcd = bx & 7;
  const int i = bx >> 3;
  const int bh = (xcd << 2) | (i & 3);
  const int chunk = i >> 2;
  const int tid = threadIdx.x;
  float aw[KTOP];
  int dl[KTOP];
#pragma unroll
  for (int j = 0; j < KTOP; ++j) {
    aw[j] = attn[bh * KTOP + j];
    dl[j] = delays[bh * KTOP + j];
  }
  const int e = chunk * 1024 + tid * 4;
  const int t = e >> 6;
  const int d = e & 63;
  const float* vb = v + (size_t)bh * LEN * DH;
  float4 acc = make_float4(0.f, 0.f, 0.f, 0.f);
#pragma unroll
  for (int j = 0; j < KTOP; ++j) {
    int src = t - dl[j];
    if (src < 0) src += LEN;
    const float4 vv = *reinterpret_cast<const float4*>(vb + (size_t)src * DH + d);
    acc.x += aw[j] * vv.x;
    acc.y += aw[j] * vv.y;
    acc.z += aw[j] * vv.z;
    acc.w += aw[j] * vv.w;
  }
  *reinterpret_cast<float4*>(out + (size_t)bh * LEN * DH + e) = acc;
}

extern "C" void kernel_launch(void* const* d_in, const int* in_sizes, int n_in,
                              void* d_out, int out_size, void* d_ws, size_t ws_size,
                              hipStream_t stream) {
  const float* q = (const float*)d_in[0];
  const float* k = (const float*)d_in[1];
  const float* v = (const float*)d_in[2];
  float* out = (float*)d_out;

  // ws layout: tw | zT (aliased as part) | spec | attn | delays  (~69.5 MB)
  const size_t need = (size_t)TW_N * 8 + ZT_ELEMS * 8 + (size_t)NBH * LEN * 8 +
                      (size_t)NBH * KTOP * 8;
  const bool tr = (ws_size >= need);

  float2* tw = (float2*)d_ws;
  float2* zT = tw + TW_N;           // 67 MB; reused in-place for partials
  float2* part = zT;                // alias: fwd overwrites slab it consumed
  float2* spec = zT + ZT_ELEMS;
  float* attn = (float*)(spec + (size_t)NBH * LEN);
  int* delays = (int*)(attn + NBH * KTOP);

  if (tr) {
    ac_transpose<<<dim3(NBH * 64), dim3(256), 0, stream>>>(q, k, zT, tw);
    ac_fft_fwd<true><<<dim3(NBH * DH), dim3(256), 0, stream>>>(q, k, zT, tw, part);
  } else {
    ac_twinit<<<dim3((TW_N + 255) / 256), dim3(256), 0, stream>>>(tw);
    ac_fft_fwd<false><<<dim3(NBH * DH), dim3(256), 0, stream>>>(q, k, zT, tw, part);
  }
  ac_reduce<<<dim3(NBH * 16), dim3(256), 0, stream>>>(part, spec);
  ac_fft_inv<<<dim3(NBH), dim3(256), 0, stream>>>(spec, tw, attn, delays);
  ac_gather<<<dim3(NBH * 256), dim3(256), 0, stream>>>(v, attn, delays, out);
}